// Round 8
// baseline (23.877 us; speedup 1.0000x reference)
//
#include <hip/hip_runtime.h>
#include <math.h>

typedef __attribute__((ext_vector_type(8))) short short8v;
typedef __attribute__((ext_vector_type(4))) float f32x4;

#define BLOCK 256

__device__ inline unsigned int pk_bf16(float lo, float hi) {
    unsigned int r;
    asm("v_cvt_pk_bf16_f32 %0, %1, %2" : "=v"(r) : "v"(lo), "v"(hi));
    return r;
}
__device__ inline short8v as_s8(uint4 v) { union { uint4 u; short8v s; } c; c.u = v; return c.s; }
__device__ inline f32x4 as_f4(float4 v) { union { float4 u; f32x4 s; } c; c.u = v; return c.s; }

__global__ __launch_bounds__(BLOCK, 4) void bnet(
    const float* __restrict__ x,
    const float* __restrict__ meanp, const float* __restrict__ stdp,
    const float* __restrict__ W1,  const float* __restrict__ b1,
    const float* __restrict__ W21, const float* __restrict__ b21,
    const float* __restrict__ W22, const float* __restrict__ b22,
    const float* __restrict__ W31, const float* __restrict__ b31,
    const float* __restrict__ W32, const float* __restrict__ b32,
    const float* __restrict__ obstacles,
    float* __restrict__ out, int nB)
{
    // Layer-1 A-frags: [g*64+lane]; lanes<16 hold W1 row 16g+m (k=0..4 w, k=5 b1).
    __shared__ uint4 w1frag[8 * 64];                  // 8 KB
    // Layer-2 A-frags with pi-permuted K (verified rounds 4/6/7).
    __shared__ uint4 fragB[16 * 64];                  // 16 KB
    __shared__ float b2s[64];                         // b21[32] | b22[32]
    __shared__ float w31s[64];                        // W31 rows 0,1
    __shared__ float w32s[64];                        // W32 rows 0,1

    const int t    = threadIdx.x;
    const int lane = t & 63;
    const int q    = lane >> 4;
    const int r15  = lane & 15;
    const bool q0  = (q == 0);

    const int pair   = blockIdx.x * 4 + (t >> 6);     // one 32-row pair per wave
    const int npairs = (nB + 31) >> 5;
    const bool valid = pair < npairs;

    // ---- issue x loads first so they overlap the staging phase ----
    float xrA[5], xrB[5];
    {
        int p  = valid ? pair : 0;
        int rA = p * 32 + r15;      if (rA >= nB) rA = nB - 1;
        int rB = p * 32 + 16 + r15; if (rB >= nB) rB = nB - 1;
        const float* pA = x + (size_t)rA * 5;
        const float* pB = x + (size_t)rB * 5;
        #pragma unroll
        for (int c = 0; c < 5; ++c) { xrA[c] = pA[c]; xrB[c] = pB[c]; }
    }

    // ---- staging (identical verified mappings) ----
    {   // zero w1frag (lanes >=16 must be zero)
        uint4 z = {0u, 0u, 0u, 0u};
        w1frag[t] = z; w1frag[t + 256] = z;
    }
    __syncthreads();
    if (t < 128) {   // W1 fragments
        int m = t & 15, g = t >> 4;
        int u = 16 * g + m;
        const float* wr = W1 + u * 5;
        uint4 v;
        v.x = pk_bf16(wr[0], wr[1]);
        v.y = pk_bf16(wr[2], wr[3]);
        v.z = pk_bf16(wr[4], b1[u]);
        v.w = 0u;
        w1frag[g * 64 + m] = v;
    }
    if (t < 64)              b2s[t]        = (t < 32) ? b21[t] : b22[t - 32];
    if (t >= 64 && t < 128)  w31s[t - 64]  = W31[t - 64];
    if (t >= 128 && t < 192) w32s[t - 128] = W32[t - 128];
    {   // layer-2 fragments (identical mapping to round 4 - verified)
        const float4* w21v = (const float4*)W21;
        const float4* w22v = (const float4*)W22;
        #pragma unroll
        for (int e = 0; e < 4; ++e) {
            int g4   = t + e * 256;
            int uo   = g4 >> 5;
            int h0   = (g4 & 31) << 2;
            int ks   = h0 >> 5;
            int jh   = (h0 >> 4) & 1;
            int qq   = (h0 >> 2) & 3;
            int ln   = (qq << 4) | (uo & 15);
            int half = uo >> 4;
            float4 f1 = w21v[g4];
            float4 f2 = w22v[g4];
            unsigned int* dA = (unsigned int*)&fragB[(half * 4 + ks) * 64 + ln];
            unsigned int* dB = (unsigned int*)&fragB[(8 + half * 4 + ks) * 64 + ln];
            dA[jh * 2] = pk_bf16(f1.x, f1.y); dA[jh * 2 + 1] = pk_bf16(f1.z, f1.w);
            dB[jh * 2] = pk_bf16(f2.x, f2.y); dB[jh * 2 + 1] = pk_bf16(f2.z, f2.w);
        }
    }
    __syncthreads();
    if (!valid) return;

    const int baseA = pair * 32;

    // ---- x B-fragments (q=0 lanes: k=0..5 = {x,1.0}) ----
    short8v xfA, xfB;
    {
        float one = q0 ? 1.0f : 0.0f;
        uint4 va, vb;
        va.x = pk_bf16(q0 ? xrA[0] : 0.f, q0 ? xrA[1] : 0.f);
        va.y = pk_bf16(q0 ? xrA[2] : 0.f, q0 ? xrA[3] : 0.f);
        va.z = pk_bf16(q0 ? xrA[4] : 0.f, one);
        va.w = 0u;
        vb.x = pk_bf16(q0 ? xrB[0] : 0.f, q0 ? xrB[1] : 0.f);
        vb.y = pk_bf16(q0 ? xrB[2] : 0.f, q0 ? xrB[3] : 0.f);
        vb.z = pk_bf16(q0 ? xrB[4] : 0.f, one);
        vb.w = 0u;
        xfA = as_s8(va); xfB = as_s8(vb);
    }

    // ---- layer 1: 16 MFMA (2 chains), W1 frags streamed from LDS ----
    short8v afA[4], afB[4];
    #pragma unroll
    for (int ks = 0; ks < 4; ++ks) {
        f32x4 z = {0.f, 0.f, 0.f, 0.f};
        short8v w0  = as_s8(w1frag[(2 * ks) * 64 + lane]);
        short8v w1v = as_s8(w1frag[(2 * ks + 1) * 64 + lane]);
        f32x4 hA0 = __builtin_amdgcn_mfma_f32_16x16x32_bf16(w0,  xfA, z, 0, 0, 0);
        f32x4 hA1 = __builtin_amdgcn_mfma_f32_16x16x32_bf16(w1v, xfA, z, 0, 0, 0);
        f32x4 hB0 = __builtin_amdgcn_mfma_f32_16x16x32_bf16(w0,  xfB, z, 0, 0, 0);
        f32x4 hB1 = __builtin_amdgcn_mfma_f32_16x16x32_bf16(w1v, xfB, z, 0, 0, 0);
        uint4 va, vb;
        va.x = pk_bf16(fmaxf(hA0[0], 0.f), fmaxf(hA0[1], 0.f));
        va.y = pk_bf16(fmaxf(hA0[2], 0.f), fmaxf(hA0[3], 0.f));
        va.z = pk_bf16(fmaxf(hA1[0], 0.f), fmaxf(hA1[1], 0.f));
        va.w = pk_bf16(fmaxf(hA1[2], 0.f), fmaxf(hA1[3], 0.f));
        vb.x = pk_bf16(fmaxf(hB0[0], 0.f), fmaxf(hB0[1], 0.f));
        vb.y = pk_bf16(fmaxf(hB0[2], 0.f), fmaxf(hB0[3], 0.f));
        vb.z = pk_bf16(fmaxf(hB1[0], 0.f), fmaxf(hB1[1], 0.f));
        vb.w = pk_bf16(fmaxf(hB1[2], 0.f), fmaxf(hB1[3], 0.f));
        afA[ks] = as_s8(va); afB[ks] = as_s8(vb);
    }

    // ---- layer 2: 32 MFMA, W2 frags streamed from LDS per-ks (transient) ----
    const float4* b2v = (const float4*)b2s;
    f32x4 a21aA = as_f4(b2v[q]);
    f32x4 a21bA = as_f4(b2v[4 + q]);
    f32x4 a22aA = as_f4(b2v[8 + q]);
    f32x4 a22bA = as_f4(b2v[12 + q]);
    f32x4 a21aB = a21aA, a21bB = a21bA, a22aB = a22aA, a22bB = a22bA;
    #pragma unroll
    for (int ks = 0; ks < 4; ++ks) {
        short8v f21a = as_s8(fragB[(     ks) * 64 + lane]);
        short8v f21b = as_s8(fragB[( 4 + ks) * 64 + lane]);
        short8v f22a = as_s8(fragB[( 8 + ks) * 64 + lane]);
        short8v f22b = as_s8(fragB[(12 + ks) * 64 + lane]);
        a21aA = __builtin_amdgcn_mfma_f32_16x16x32_bf16(f21a, afA[ks], a21aA, 0, 0, 0);
        a21aB = __builtin_amdgcn_mfma_f32_16x16x32_bf16(f21a, afB[ks], a21aB, 0, 0, 0);
        a21bA = __builtin_amdgcn_mfma_f32_16x16x32_bf16(f21b, afA[ks], a21bA, 0, 0, 0);
        a21bB = __builtin_amdgcn_mfma_f32_16x16x32_bf16(f21b, afB[ks], a21bB, 0, 0, 0);
        a22aA = __builtin_amdgcn_mfma_f32_16x16x32_bf16(f22a, afA[ks], a22aA, 0, 0, 0);
        a22aB = __builtin_amdgcn_mfma_f32_16x16x32_bf16(f22a, afB[ks], a22aB, 0, 0, 0);
        a22bA = __builtin_amdgcn_mfma_f32_16x16x32_bf16(f22b, afA[ks], a22bA, 0, 0, 0);
        a22bB = __builtin_amdgcn_mfma_f32_16x16x32_bf16(f22b, afB[ks], a22bB, 0, 0, 0);
    }

    // ---- heads: relu'd values, coefficients streamed from LDS per head ----
    float vA21[8], vA22[8], vB21[8], vB22[8];
    #pragma unroll
    for (int r = 0; r < 4; ++r) {
        vA21[r] = fmaxf(a21aA[r], 0.f); vA21[4 + r] = fmaxf(a21bA[r], 0.f);
        vA22[r] = fmaxf(a22aA[r], 0.f); vA22[4 + r] = fmaxf(a22bA[r], 0.f);
        vB21[r] = fmaxf(a21aB[r], 0.f); vB21[4 + r] = fmaxf(a21bB[r], 0.f);
        vB22[r] = fmaxf(a22aB[r], 0.f); vB22[4 + r] = fmaxf(a22bB[r], 0.f);
    }
    float pA[4], pB[4];
    #pragma unroll
    for (int hsel = 0; hsel < 4; ++hsel) {
        const float* cof = (hsel < 2) ? w31s : w32s;
        const float* vavA = (hsel < 2) ? vA21 : vA22;
        const float* vavB = (hsel < 2) ? vB21 : vB22;
        int off = (hsel & 1) * 32;
        float4 clo = *(const float4*)(cof + off + 4 * q);
        float4 chi = *(const float4*)(cof + off + 16 + 4 * q);
        float sA = 0.f, sB = 0.f;
        sA = fmaf(vavA[0], clo.x, sA); sA = fmaf(vavA[1], clo.y, sA);
        sA = fmaf(vavA[2], clo.z, sA); sA = fmaf(vavA[3], clo.w, sA);
        sA = fmaf(vavA[4], chi.x, sA); sA = fmaf(vavA[5], chi.y, sA);
        sA = fmaf(vavA[6], chi.z, sA); sA = fmaf(vavA[7], chi.w, sA);
        sB = fmaf(vavB[0], clo.x, sB); sB = fmaf(vavB[1], clo.y, sB);
        sB = fmaf(vavB[2], clo.z, sB); sB = fmaf(vavB[3], clo.w, sB);
        sB = fmaf(vavB[4], chi.x, sB); sB = fmaf(vavB[5], chi.y, sB);
        sB = fmaf(vavB[6], chi.z, sB); sB = fmaf(vavB[7], chi.w, sB);
        // reduce across q-groups
        sA += __shfl_xor(sA, 16); sA += __shfl_xor(sA, 32);
        sB += __shfl_xor(sB, 16); sB += __shfl_xor(sB, 32);
        pA[hsel] = sA; pB[hsel] = sB;
    }

    // ---- epilogue: lanes 0..31 own rows baseA..baseA+31 ----
    if (lane < 32) {
        const bool sa = (lane < 16);
        // uniform scalars (compiler emits s_load): b31/b32, mean/std, obstacles
        float x31_0 = (sa ? pA[0] : pB[0]) + b31[0];
        float x31_1 = (sa ? pA[1] : pB[1]) + b31[1];
        float t32_0 = (sa ? pA[2] : pB[2]) + b32[0];
        float t32_1 = (sa ? pA[3] : pB[3]) + b32[1];

        float s0v = __fdividef(4.f, 1.f + __expf(-t32_0));
        float s1v = __fdividef(4.f, 1.f + __expf(-t32_1));
        float hcoef = s0v * s1v;

        float xo[5];
        #pragma unroll
        for (int c = 0; c < 5; ++c) {
            float m = meanp[c], s = stdp[c];
            float xc = sa ? xrA[c] : xrB[c];
            float x0 = fmaf(xc, s, m);
            xo[c] = fmaf(x0, s, m);
        }
        float px = xo[0], py = xo[1], th = xo[2], oppx = xo[3], oppy = xo[4];
        float st, ct;
        __sincosf(th, &st, &ct);

        float upper = INFINITY, lower = -INFINITY;
        #pragma unroll
        for (int j = 0; j < 9; ++j) {
            float ox, oy, rr2;
            if (j < 8) {
                ox = obstacles[j * 3];
                oy = obstacles[j * 3 + 1];
                float rr = obstacles[j * 3 + 2];
                rr2 = rr * rr;
            } else {
                ox = oppx; oy = oppy; rr2 = 0.3f * 0.3f;
            }
            float dx = px - ox, dy = py - oy;
            float bar = fmaf(dx, dx, fmaf(dy, dy, -rr2));
            float g1  = -2.f * fmaf(dx, ct, dy * st);
            float ratio = __fdividef(hcoef * bar, (g1 != 0.f) ? g1 : 1.f);
            if (g1 > 0.f) upper = fminf(upper, ratio);
            if (g1 < 0.f) lower = fmaxf(lower, ratio);
        }
        float u1 = fminf(fmaxf(-x31_0, lower), upper);
        float u2 = -x31_1;

        int row = baseA + lane;
        if (row < nB) {
            float2 o; o.x = u1; o.y = u2;
            *reinterpret_cast<float2*>(out + 2 * (size_t)row) = o;
        }
    }
}

extern "C" void kernel_launch(void* const* d_in, const int* in_sizes, int n_in,
                              void* d_out, int out_size, void* d_ws, size_t ws_size,
                              hipStream_t stream) {
    const float* x         = (const float*)d_in[0];
    const float* meanp     = (const float*)d_in[1];
    const float* stdp      = (const float*)d_in[2];
    const float* W1        = (const float*)d_in[3];
    const float* b1        = (const float*)d_in[4];
    const float* W21       = (const float*)d_in[5];
    const float* b21       = (const float*)d_in[6];
    const float* W22       = (const float*)d_in[7];
    const float* b22       = (const float*)d_in[8];
    const float* W31       = (const float*)d_in[9];
    const float* b31       = (const float*)d_in[10];
    const float* W32       = (const float*)d_in[11];
    const float* b32       = (const float*)d_in[12];
    const float* obstacles = (const float*)d_in[13];
    float* out = (float*)d_out;

    int nB = in_sizes[0] / 5;
    int npairs = (nB + 31) / 32;
    int grid = (npairs + 3) / 4;          // 4 waves (pairs) per block
    bnet<<<grid, BLOCK, 0, stream>>>(
        x, meanp, stdp, W1, b1, W21, b21, W22, b22,
        W31, b31, W32, b32, obstacles, out, nB);
}

// Round 9
// 19.756 us; speedup vs baseline: 1.2086x; 1.2086x over previous
//
#include <hip/hip_runtime.h>
#include <math.h>

typedef __attribute__((ext_vector_type(8))) short short8v;
typedef __attribute__((ext_vector_type(4))) float f32x4;

#define BLOCK 256
#define GRID  512

__device__ inline unsigned int pk_bf16(float lo, float hi) {
    unsigned int r;
    asm("v_cvt_pk_bf16_f32 %0, %1, %2" : "=v"(r) : "v"(lo), "v"(hi));
    return r;
}
__device__ inline short8v as_s8(uint4 v) { union { uint4 u; short8v s; } c; c.u = v; return c.s; }
__device__ inline f32x4 as_f4(float4 v) { union { float4 u; f32x4 s; } c; c.u = v; return c.s; }

__global__ __launch_bounds__(BLOCK, 2) void bnet(
    const float* __restrict__ x,
    const float* __restrict__ meanp, const float* __restrict__ stdp,
    const float* __restrict__ W1,  const float* __restrict__ b1,
    const float* __restrict__ W21, const float* __restrict__ b21,
    const float* __restrict__ W22, const float* __restrict__ b22,
    const float* __restrict__ W31, const float* __restrict__ b31,
    const float* __restrict__ W32, const float* __restrict__ b32,
    const float* __restrict__ obstacles,
    float* __restrict__ out, int nB)
{
    // Layer-1 A-frags: [g*64+lane]; lanes<16 hold W1 row 16g+m (k=0..4 w, k=5 b1).
    __shared__ uint4 w1frag[8 * 64];                  // 8 KB
    // Layer-2 A-frags with pi-permuted K (verified rounds 4..8).
    __shared__ uint4 fragB[16 * 64];                  // 16 KB
    // Head A-frags (verified round 6): ks=0 -> W31 rows 0/1 at m=0/1 over
    // sigma-permuted x21 units; ks=1 -> W32 rows 0/1 at m=2/3 over x22 units.
    __shared__ uint4 headA[2 * 64];                   // 2 KB
    __shared__ float b2s[64];                         // b21[32] | b22[32]

    const int t = threadIdx.x;

    {   // zero w1frag (lanes >=16 must be zero)
        uint4 z = {0u, 0u, 0u, 0u};
        w1frag[t] = z; w1frag[t + 256] = z;
    }
    __syncthreads();
    if (t < 128) {   // W1 fragments
        int m = t & 15, g = t >> 4;
        int u = 16 * g + m;
        const float* wr = W1 + u * 5;
        uint4 v;
        v.x = pk_bf16(wr[0], wr[1]);
        v.y = pk_bf16(wr[2], wr[3]);
        v.z = pk_bf16(wr[4], b1[u]);
        v.w = 0u;
        w1frag[g * 64 + m] = v;
    } else {         // head A-fragments (threads 128..255) - round 6 verified
        int e  = t - 128;
        int ks = e >> 6, l = e & 63, m = l & 15, qq = l >> 4;
        float v[8];
        #pragma unroll
        for (int j = 0; j < 8; ++j) {
            int u = 16 * ((j >> 2) & 1) + 4 * qq + (j & 3);   // sigma^-1
            float val = 0.f;
            if (m == 0 && ks == 0) val = W31[u];
            if (m == 1 && ks == 0) val = W31[32 + u];
            if (m == 2 && ks == 1) val = W32[u];
            if (m == 3 && ks == 1) val = W32[32 + u];
            v[j] = val;
        }
        uint4 h;
        h.x = pk_bf16(v[0], v[1]); h.y = pk_bf16(v[2], v[3]);
        h.z = pk_bf16(v[4], v[5]); h.w = pk_bf16(v[6], v[7]);
        headA[ks * 64 + l] = h;
    }
    if (t < 64) b2s[t] = (t < 32) ? b21[t] : b22[t - 32];
    {   // layer-2 fragments (verified mapping)
        const float4* w21v = (const float4*)W21;
        const float4* w22v = (const float4*)W22;
        #pragma unroll
        for (int e = 0; e < 4; ++e) {
            int g4   = t + e * 256;
            int uo   = g4 >> 5;
            int h0   = (g4 & 31) << 2;
            int ks   = h0 >> 5;
            int jh   = (h0 >> 4) & 1;
            int qq   = (h0 >> 2) & 3;
            int ln   = (qq << 4) | (uo & 15);
            int half = uo >> 4;
            float4 f1 = w21v[g4];
            float4 f2 = w22v[g4];
            unsigned int* dA = (unsigned int*)&fragB[(half * 4 + ks) * 64 + ln];
            unsigned int* dB = (unsigned int*)&fragB[(8 + half * 4 + ks) * 64 + ln];
            dA[jh * 2] = pk_bf16(f1.x, f1.y); dA[jh * 2 + 1] = pk_bf16(f1.z, f1.w);
            dB[jh * 2] = pk_bf16(f2.x, f2.y); dB[jh * 2 + 1] = pk_bf16(f2.z, f2.w);
        }
    }
    __syncthreads();

    const int lane = t & 63;
    const int q    = lane >> 4;
    const int r15  = lane & 15;
    const int wid    = blockIdx.x * 4 + (t >> 6);
    const int nwaves = GRID * 4;
    const int npairs = (nB + 31) >> 5;
    if (wid >= npairs) return;

    // Resident: W2 fragments (64 VGPR) + head A-frags (8 VGPR).
    short8v bfr[16];
    #pragma unroll
    for (int i = 0; i < 16; ++i) bfr[i] = as_s8(fragB[i * 64 + lane]);
    const short8v hA0 = as_s8(headA[lane]);
    const short8v hA1 = as_s8(headA[64 + lane]);
    const float4* b2v = (const float4*)b2s;

    const float hb0 = b31[0], hb1 = b31[1], hb2 = b32[0], hb3 = b32[1];

    // Full MLP for a 32-row pair: x (per-lane rows r15 / 16+r15) -> heads.
    // Heads for rows 0..15 of each chain land on lanes 0..15 as f32x4.
    auto MLP = [&](const float xA[5], const float xB[5], f32x4& hdA, f32x4& hdB) {
        uint4 va, vb;
        va.x = pk_bf16(xA[0], xA[1]); va.y = pk_bf16(xA[2], xA[3]);
        va.z = pk_bf16(xA[4], 1.0f);  va.w = 0u;
        vb.x = pk_bf16(xB[0], xB[1]); vb.y = pk_bf16(xB[2], xB[3]);
        vb.z = pk_bf16(xB[4], 1.0f);  vb.w = 0u;
        short8v xfA = as_s8(va), xfB = as_s8(vb);

        // layer 1: 16 MFMA (2 chains), relu+pack fused
        short8v afA[4], afB[4];
        #pragma unroll
        for (int ks = 0; ks < 4; ++ks) {
            f32x4 z = {0.f, 0.f, 0.f, 0.f};
            short8v w0  = as_s8(w1frag[(2 * ks) * 64 + lane]);
            short8v w1v = as_s8(w1frag[(2 * ks + 1) * 64 + lane]);
            f32x4 hA0_ = __builtin_amdgcn_mfma_f32_16x16x32_bf16(w0,  xfA, z, 0, 0, 0);
            f32x4 hA1_ = __builtin_amdgcn_mfma_f32_16x16x32_bf16(w1v, xfA, z, 0, 0, 0);
            f32x4 hB0_ = __builtin_amdgcn_mfma_f32_16x16x32_bf16(w0,  xfB, z, 0, 0, 0);
            f32x4 hB1_ = __builtin_amdgcn_mfma_f32_16x16x32_bf16(w1v, xfB, z, 0, 0, 0);
            uint4 pa, pb;
            pa.x = pk_bf16(fmaxf(hA0_[0], 0.f), fmaxf(hA0_[1], 0.f));
            pa.y = pk_bf16(fmaxf(hA0_[2], 0.f), fmaxf(hA0_[3], 0.f));
            pa.z = pk_bf16(fmaxf(hA1_[0], 0.f), fmaxf(hA1_[1], 0.f));
            pa.w = pk_bf16(fmaxf(hA1_[2], 0.f), fmaxf(hA1_[3], 0.f));
            pb.x = pk_bf16(fmaxf(hB0_[0], 0.f), fmaxf(hB0_[1], 0.f));
            pb.y = pk_bf16(fmaxf(hB0_[2], 0.f), fmaxf(hB0_[3], 0.f));
            pb.z = pk_bf16(fmaxf(hB1_[0], 0.f), fmaxf(hB1_[1], 0.f));
            pb.w = pk_bf16(fmaxf(hB1_[2], 0.f), fmaxf(hB1_[3], 0.f));
            afA[ks] = as_s8(pa); afB[ks] = as_s8(pb);
        }

        // layer 2: 32 MFMA, bias-initialized accumulators (LDS broadcast)
        f32x4 a21aA = as_f4(b2v[q]);
        f32x4 a21bA = as_f4(b2v[4 + q]);
        f32x4 a22aA = as_f4(b2v[8 + q]);
        f32x4 a22bA = as_f4(b2v[12 + q]);
        f32x4 a21aB = a21aA, a21bB = a21bA, a22aB = a22aA, a22bB = a22bA;
        #pragma unroll
        for (int ks = 0; ks < 4; ++ks) {
            a21aA = __builtin_amdgcn_mfma_f32_16x16x32_bf16(bfr[     ks], afA[ks], a21aA, 0, 0, 0);
            a21aB = __builtin_amdgcn_mfma_f32_16x16x32_bf16(bfr[     ks], afB[ks], a21aB, 0, 0, 0);
            a21bA = __builtin_amdgcn_mfma_f32_16x16x32_bf16(bfr[ 4 + ks], afA[ks], a21bA, 0, 0, 0);
            a21bB = __builtin_amdgcn_mfma_f32_16x16x32_bf16(bfr[ 4 + ks], afB[ks], a21bB, 0, 0, 0);
            a22aA = __builtin_amdgcn_mfma_f32_16x16x32_bf16(bfr[ 8 + ks], afA[ks], a22aA, 0, 0, 0);
            a22aB = __builtin_amdgcn_mfma_f32_16x16x32_bf16(bfr[ 8 + ks], afB[ks], a22aB, 0, 0, 0);
            a22bA = __builtin_amdgcn_mfma_f32_16x16x32_bf16(bfr[12 + ks], afA[ks], a22bA, 0, 0, 0);
            a22bB = __builtin_amdgcn_mfma_f32_16x16x32_bf16(bfr[12 + ks], afB[ks], a22bB, 0, 0, 0);
        }

        // heads: relu+pack into sigma-ordered B-fragments, 2 MFMA per chain
        uint4 h1A, h2A, h1B, h2B;
        h1A.x = pk_bf16(fmaxf(a21aA[0], 0.f), fmaxf(a21aA[1], 0.f));
        h1A.y = pk_bf16(fmaxf(a21aA[2], 0.f), fmaxf(a21aA[3], 0.f));
        h1A.z = pk_bf16(fmaxf(a21bA[0], 0.f), fmaxf(a21bA[1], 0.f));
        h1A.w = pk_bf16(fmaxf(a21bA[2], 0.f), fmaxf(a21bA[3], 0.f));
        h2A.x = pk_bf16(fmaxf(a22aA[0], 0.f), fmaxf(a22aA[1], 0.f));
        h2A.y = pk_bf16(fmaxf(a22aA[2], 0.f), fmaxf(a22aA[3], 0.f));
        h2A.z = pk_bf16(fmaxf(a22bA[0], 0.f), fmaxf(a22bA[1], 0.f));
        h2A.w = pk_bf16(fmaxf(a22bA[2], 0.f), fmaxf(a22bA[3], 0.f));
        h1B.x = pk_bf16(fmaxf(a21aB[0], 0.f), fmaxf(a21aB[1], 0.f));
        h1B.y = pk_bf16(fmaxf(a21aB[2], 0.f), fmaxf(a21aB[3], 0.f));
        h1B.z = pk_bf16(fmaxf(a21bB[0], 0.f), fmaxf(a21bB[1], 0.f));
        h1B.w = pk_bf16(fmaxf(a21bB[2], 0.f), fmaxf(a21bB[3], 0.f));
        h2B.x = pk_bf16(fmaxf(a22aB[0], 0.f), fmaxf(a22aB[1], 0.f));
        h2B.y = pk_bf16(fmaxf(a22aB[2], 0.f), fmaxf(a22aB[3], 0.f));
        h2B.z = pk_bf16(fmaxf(a22bB[0], 0.f), fmaxf(a22bB[1], 0.f));
        h2B.w = pk_bf16(fmaxf(a22bB[2], 0.f), fmaxf(a22bB[3], 0.f));

        f32x4 ini = {hb0, hb1, hb2, hb3};
        hdA = __builtin_amdgcn_mfma_f32_16x16x32_bf16(hA0, as_s8(h1A), ini, 0, 0, 0);
        hdA = __builtin_amdgcn_mfma_f32_16x16x32_bf16(hA1, as_s8(h2A), hdA, 0, 0, 0);
        hdB = __builtin_amdgcn_mfma_f32_16x16x32_bf16(hA0, as_s8(h1B), ini, 0, 0, 0);
        hdB = __builtin_amdgcn_mfma_f32_16x16x32_bf16(hA1, as_s8(h2B), hdB, 0, 0, 0);
    };

    auto LOADX = [&](int p, float xA[5], float xB[5]) {
        int rA = p * 32 + r15;      if (rA >= nB) rA = nB - 1;
        int rB = p * 32 + 16 + r15; if (rB >= nB) rB = nB - 1;
        const float* pA = x + (size_t)rA * 5;
        const float* pB = x + (size_t)rB * 5;
        #pragma unroll
        for (int c = 0; c < 5; ++c) { xA[c] = pA[c]; xB[c] = pB[c]; }
    };

    // ---- software-pipelined loop: MLP(next) issued before EPILOGUE(cur) ----
    int p = wid;
    float xrA[5], xrB[5];
    LOADX(p, xrA, xrB);
    f32x4 hdA, hdB;
    MLP(xrA, xrB, hdA, hdB);

    while (true) {
        const int nxt = p + nwaves;
        const bool has = nxt < npairs;
        float xnA[5], xnB[5];
        f32x4 hdA2, hdB2;
        if (has) {            // next tile's MLP: MFMA-pipe work, independent
            LOADX(nxt, xnA, xnB);
            MLP(xnA, xnB, hdA2, hdB2);
        }

        // ---- epilogue(cur): VALU/trans work, overlaps the MFMAs above ----
        {
            float hs0 = __shfl(hdB[0], r15);
            float hs1 = __shfl(hdB[1], r15);
            float hs2 = __shfl(hdB[2], r15);
            float hs3 = __shfl(hdB[3], r15);
            if (lane < 32) {
                const bool sa = (lane < 16);
                float x31_0 = sa ? hdA[0] : hs0;
                float x31_1 = sa ? hdA[1] : hs1;
                float t32_0 = sa ? hdA[2] : hs2;
                float t32_1 = sa ? hdA[3] : hs3;

                float s0v = __fdividef(4.f, 1.f + __expf(-t32_0));
                float s1v = __fdividef(4.f, 1.f + __expf(-t32_1));
                float hcoef = s0v * s1v;

                float xo[5];
                #pragma unroll
                for (int c = 0; c < 5; ++c) {
                    float m = meanp[c], s = stdp[c];
                    float xc = sa ? xrA[c] : xrB[c];
                    float x0 = fmaf(xc, s, m);
                    xo[c] = fmaf(x0, s, m);
                }
                float px = xo[0], py = xo[1], th = xo[2], oppx = xo[3], oppy = xo[4];
                float st, ct;
                __sincosf(th, &st, &ct);

                float upper = INFINITY, lower = -INFINITY;
                #pragma unroll
                for (int j = 0; j < 9; ++j) {
                    float ox, oy, rr2;
                    if (j < 8) {
                        ox = obstacles[j * 3];
                        oy = obstacles[j * 3 + 1];
                        float rr = obstacles[j * 3 + 2];
                        rr2 = rr * rr;
                    } else {
                        ox = oppx; oy = oppy; rr2 = 0.3f * 0.3f;
                    }
                    float dx = px - ox, dy = py - oy;
                    float bar = fmaf(dx, dx, fmaf(dy, dy, -rr2));
                    float g1  = -2.f * fmaf(dx, ct, dy * st);
                    float ratio = __fdividef(hcoef * bar, (g1 != 0.f) ? g1 : 1.f);
                    if (g1 > 0.f) upper = fminf(upper, ratio);
                    if (g1 < 0.f) lower = fmaxf(lower, ratio);
                }
                float u1 = fminf(fmaxf(-x31_0, lower), upper);
                float u2 = -x31_1;

                int row = p * 32 + lane;
                if (row < nB) {
                    float2 o; o.x = u1; o.y = u2;
                    *reinterpret_cast<float2*>(out + 2 * (size_t)row) = o;
                }
            }
        }

        if (!has) break;
        p = nxt;
        #pragma unroll
        for (int c = 0; c < 5; ++c) { xrA[c] = xnA[c]; xrB[c] = xnB[c]; }
        hdA = hdA2; hdB = hdB2;
    }
}

extern "C" void kernel_launch(void* const* d_in, const int* in_sizes, int n_in,
                              void* d_out, int out_size, void* d_ws, size_t ws_size,
                              hipStream_t stream) {
    const float* x         = (const float*)d_in[0];
    const float* meanp     = (const float*)d_in[1];
    const float* stdp      = (const float*)d_in[2];
    const float* W1        = (const float*)d_in[3];
    const float* b1        = (const float*)d_in[4];
    const float* W21       = (const float*)d_in[5];
    const float* b21       = (const float*)d_in[6];
    const float* W22       = (const float*)d_in[7];
    const float* b22       = (const float*)d_in[8];
    const float* W31       = (const float*)d_in[9];
    const float* b31       = (const float*)d_in[10];
    const float* W32       = (const float*)d_in[11];
    const float* b32       = (const float*)d_in[12];
    const float* obstacles = (const float*)d_in[13];
    float* out = (float*)d_out;

    int nB = in_sizes[0] / 5;
    bnet<<<GRID, BLOCK, 0, stream>>>(
        x, meanp, stdp, W1, b1, W21, b21, W22, b22,
        W31, b31, W32, b32, obstacles, out, nB);
}